// Round 5
// baseline (44518.845 us; speedup 1.0000x reference)
//
#include <hip/hip_runtime.h>
#include <math.h>

#pragma clang fp contract(off)

#define DD 384
#define NS 96
#define PB 32     // panel width (pivots per panel)
#define PW 388    // sp row stride (floats)
#define NW 16     // waves per block

// A = I - P P^T, full symmetric matrix (P = eigfunc[:, :NS])
__global__ void build_A_kernel(const float* __restrict__ eig, float* __restrict__ A) {
    int idx = blockIdx.x * blockDim.x + threadIdx.x;
    if (idx >= DD * DD) return;
    int j = idx / DD, z = idx - j * DD;
    const float* rj = eig + (size_t)j * DD;
    const float* rz = eig + (size_t)z * DD;
    float s = 0.0f;
    for (int c = 0; c < NS; ++c) s = fmaf(rj[c], rz[c], s);
    A[(size_t)j * DD + z] = ((j == z) ? 1.0f : 0.0f) - s;
}

// Stash: factored pivot row b, col c (c > b) stored at W[(DD-1-b)*DD + (DD-1-c)]
// = strict LOWER triangle of W (spec trailing uses only W's upper incl. diag).
__device__ __forceinline__ size_t stash_idx(int b, int c) {
    return (size_t)(DD - 1 - b) * DD + (DD - 1 - c);
}

__global__ __launch_bounds__(1024) void sampler_kernel(const float* __restrict__ u,
                                                       float* __restrict__ A,
                                                       float* __restrict__ W,
                                                       float* __restrict__ out) {
    __shared__ float sblk[PB * 33];   // factored diag block (upper used)
    __shared__ float sp[PB * PW];     // panel rows, local col j = global_col - x0 (j >= bs)
    __shared__ float sinv[PB];
    __shared__ float pivL[DD];
    __shared__ float probs[DD];
    __shared__ float sinvC[DD];
    __shared__ int s_pos;

    const int t = threadIdx.x;
    const int wid = t >> 6;
    const int lane = t & 63;
    const int lr = lane >> 4;   // 0..3
    const int lc = lane & 15;   // 0..15

    int xbase = 0;
    for (int k = 0; k < NS; ++k) {
        const int xmax = DD - NS + k + 1;

        // ================= SPEC: pivots [xbase, xmax), full width to DD =================
        for (int x0 = xbase; x0 < xmax; x0 += PB) {
            const int rem = xmax - x0;
            const int bs = (rem < PB) ? rem : PB;
            const int width = DD - x0;
            const float* SRC = (x0 == xbase) ? A : W;
            const bool last = (x0 + PB >= xmax);

            if (wid == 0) {
                // ---- register-resident diag-block factorization (lanes 0..31) ----
                if (lane < 32) {
                    const int c = lane;
                    float w[PB];
                    #pragma unroll
                    for (int r = 0; r < PB; ++r) {
                        w[r] = 0.0f;
                        if (r <= c && c < bs) w[r] = SRC[(size_t)(x0 + r) * DD + (x0 + c)];
                    }
                    #pragma unroll
                    for (int x = 0; x < PB; ++x) {
                        const float wx = w[x];                 // block[x][c] (final entering iter x)
                        const float p = __shfl(wx, x);         // block[x][x]
                        const float inv = (fabsf(p) > 1e-30f) ? (1.0f / p) : 0.0f;
                        if (x < bs && lane == 0) { sinv[x] = inv; pivL[x0 + x] = p; }
                        #pragma unroll
                        for (int r = x + 1; r < PB; ++r) {
                            const float br = __shfl(wx, r);    // block[x][r]
                            if (r < bs && c >= r) {
                                float cc = inv * (br * wx);    // inv*(cy*cz), ref order
                                w[r] = w[r] - cc;
                            }
                        }
                    }
                    // write factored block to LDS (solve) + stash strict-super part
                    #pragma unroll
                    for (int r = 0; r < PB; ++r) {
                        if (r <= c && c < bs) {
                            sblk[r * 33 + c] = w[r];
                            if (r < c) W[stash_idx(x0 + r, x0 + c)] = w[r];
                        }
                    }
                }
            } else {
                // ---- waves 1..15: load panel rows, off-diag cols [bs, width) ----
                for (int i = wid - 1; i < bs; i += NW - 1) {
                    const float* srow = SRC + (size_t)(x0 + i) * DD + x0;
                    for (int j = bs + lane; j < width; j += 64)
                        sp[i * PW + j] = srow[j];
                }
            }
            __syncthreads();

            // ---- panel-row solve: one col per thread, registers, unrolled; + stash ----
            for (int j = bs + t; j < width; j += 1024) {
                float w[PB];
                #pragma unroll
                for (int i = 0; i < PB; ++i)
                    w[i] = (i < bs) ? sp[i * PW + j] : 0.0f;
                #pragma unroll
                for (int b = 0; b < PB - 1; ++b) {
                    if (b < bs - 1) {
                        const float invb = sinv[b];
                        const float wb = w[b];
                        #pragma unroll
                        for (int i = b + 1; i < PB; ++i) {
                            if (i < bs) {
                                float cc = invb * (sblk[b * 33 + i] * wb);
                                w[i] = w[i] - cc;
                            }
                        }
                    }
                }
                const int cg = x0 + j;
                #pragma unroll
                for (int i = 0; i < PB; ++i) {
                    if (i < bs) {
                        sp[i * PW + j] = w[i];
                        W[stash_idx(x0 + i, cg)] = w[i];
                    }
                }
            }
            __syncthreads();

            // ---- trailing rank-32 update (skipped for last panel): SRC -> W upper ----
            if (!last) {
                const int tb = x0 + PB;
                int tile = 0;
                for (int ty = tb; ty < DD; ty += 16) {
                    for (int tz = ty; tz < DD; tz += 64) {
                        if ((tile++ & (NW - 1)) != wid) continue;
                        const int ybase = ty + 4 * lr;
                        const int zbase = tz + lc;
                        float wv[4][4];
                        const bool fast = (tz != ty) && (ty + 16 <= DD) && (tz + 64 <= DD);
                        if (fast) {
                            #pragma unroll
                            for (int yi = 0; yi < 4; ++yi) {
                                const float* srow = SRC + (size_t)(ybase + yi) * DD;
                                #pragma unroll
                                for (int zi = 0; zi < 4; ++zi)
                                    wv[yi][zi] = srow[zbase + 16 * zi];
                            }
                            for (int b = 0; b < PB; ++b) {
                                const float inv = sinv[b];
                                float cy[4], cz[4];
                                #pragma unroll
                                for (int yi = 0; yi < 4; ++yi) cy[yi] = sp[b * PW + (ybase + yi - x0)];
                                #pragma unroll
                                for (int zi = 0; zi < 4; ++zi) cz[zi] = sp[b * PW + (zbase + 16 * zi - x0)];
                                #pragma unroll
                                for (int yi = 0; yi < 4; ++yi) {
                                    #pragma unroll
                                    for (int zi = 0; zi < 4; ++zi) {
                                        float c = inv * (cy[yi] * cz[zi]);
                                        wv[yi][zi] = wv[yi][zi] - c;
                                    }
                                }
                            }
                            #pragma unroll
                            for (int yi = 0; yi < 4; ++yi) {
                                float* drow = W + (size_t)(ybase + yi) * DD;
                                #pragma unroll
                                for (int zi = 0; zi < 4; ++zi)
                                    drow[zbase + 16 * zi] = wv[yi][zi];
                            }
                        } else {
                            #pragma unroll
                            for (int yi = 0; yi < 4; ++yi) {
                                const int y = ybase + yi;
                                #pragma unroll
                                for (int zi = 0; zi < 4; ++zi) {
                                    const int z = zbase + 16 * zi;
                                    float v = 0.0f;
                                    if (y < DD && z < DD && z >= y) v = SRC[(size_t)y * DD + z];
                                    wv[yi][zi] = v;
                                }
                            }
                            for (int b = 0; b < PB; ++b) {
                                const float inv = sinv[b];
                                #pragma unroll
                                for (int yi = 0; yi < 4; ++yi) {
                                    const int y = ybase + yi;
                                    const int yy = (y < DD) ? (y - x0) : PB;   // safe LDS index
                                    const float cy = sp[b * PW + yy];
                                    #pragma unroll
                                    for (int zi = 0; zi < 4; ++zi) {
                                        const int z = zbase + 16 * zi;
                                        const int zz = (z < DD) ? (z - x0) : PB;
                                        const float cz = sp[b * PW + zz];
                                        float c = inv * (cy * cz);
                                        wv[yi][zi] = wv[yi][zi] - c;
                                    }
                                }
                            }
                            #pragma unroll
                            for (int yi = 0; yi < 4; ++yi) {
                                const int y = ybase + yi;
                                #pragma unroll
                                for (int zi = 0; zi < 4; ++zi) {
                                    const int z = zbase + 16 * zi;
                                    if (y < DD && z < DD && z >= y)
                                        W[(size_t)y * DD + z] = wv[yi][zi];
                                }
                            }
                        }
                    }
                }
                __syncthreads();
            }
        }

        // ================= SAMPLING (t==0, bit-faithful to reference) =================
        if (t == 0) {
            float cp = 1.0f;
            float tot = 0.0f;
            for (int x = xbase; x < xmax; ++x) {
                const float p = pivL[x];
                float pr = cp * (1.0f - p);
                if (!(fabsf(pr) > 1e-15f)) pr = 0.0f;
                probs[x] = pr;
                tot = tot + pr;
                cp = cp * p;
            }
            const float uk = u[k];
            const float target = uk * tot;
            int cnt = (target > 0.0f) ? xbase : 0;   // zeros below window
            float run = 0.0f;
            for (int x = xbase; x < xmax; ++x) {
                run = run + probs[x];
                if (run < target) ++cnt;
            }
            if (tot < target) cnt += DD - xmax;      // zeros above window
            int pos = (cnt < xmax - 1) ? cnt : (xmax - 1);
            s_pos = pos;
            out[k] = (float)pos;
            out[NS + k] = (pos >= xbase) ? probs[pos] : 0.0f;
        }
        __syncthreads();
        const int pos = s_pos;

        // ================= COMMIT: one rank-R pass on A over [pos+1, DD)^2 =================
        // invs from spec pivots; only pos's pivot gets the occupancy -1 (same fp as R1-R3).
        for (int b = xbase + t; b <= pos; b += 1024) {
            float p = pivL[b];
            if (b == pos) p = p - 1.0f;
            sinvC[b] = (fabsf(p) > 1e-30f) ? (1.0f / p) : 0.0f;
        }
        __syncthreads();

        const int tb = pos + 1;
        if (tb < DD) {
            int tile = 0;
            for (int ty = tb; ty < DD; ty += 16) {
                for (int tz = ty; tz < DD; tz += 64) {
                    if ((tile++ & (NW - 1)) != wid) continue;
                    const int ybase = ty + 4 * lr;
                    const int zbase = tz + lc;
                    float wv[4][4];
                    const bool fast = (tz != ty) && (ty + 16 <= DD) && (tz + 64 <= DD);
                    if (fast) {
                        #pragma unroll
                        for (int yi = 0; yi < 4; ++yi) {
                            const float* srow = A + (size_t)(ybase + yi) * DD;
                            #pragma unroll
                            for (int zi = 0; zi < 4; ++zi)
                                wv[yi][zi] = srow[zbase + 16 * zi];
                        }
                        #pragma unroll 4
                        for (int b = xbase; b <= pos; ++b) {
                            const float inv = sinvC[b];
                            const float* srow = W + (size_t)(DD - 1 - b) * DD;
                            float cy[4], cz[4];
                            #pragma unroll
                            for (int yi = 0; yi < 4; ++yi) cy[yi] = srow[DD - 1 - (ybase + yi)];
                            #pragma unroll
                            for (int zi = 0; zi < 4; ++zi) cz[zi] = srow[DD - 1 - (zbase + 16 * zi)];
                            #pragma unroll
                            for (int yi = 0; yi < 4; ++yi) {
                                #pragma unroll
                                for (int zi = 0; zi < 4; ++zi) {
                                    float c = inv * (cy[yi] * cz[zi]);
                                    wv[yi][zi] = wv[yi][zi] - c;
                                }
                            }
                        }
                        #pragma unroll
                        for (int yi = 0; yi < 4; ++yi) {
                            float* drow = A + (size_t)(ybase + yi) * DD;
                            #pragma unroll
                            for (int zi = 0; zi < 4; ++zi)
                                drow[zbase + 16 * zi] = wv[yi][zi];
                        }
                    } else {
                        #pragma unroll
                        for (int yi = 0; yi < 4; ++yi) {
                            const int y = ybase + yi;
                            #pragma unroll
                            for (int zi = 0; zi < 4; ++zi) {
                                const int z = zbase + 16 * zi;
                                float v = 0.0f;
                                if (y < DD && z < DD && z >= y) v = A[(size_t)y * DD + z];
                                wv[yi][zi] = v;
                            }
                        }
                        for (int b = xbase; b <= pos; ++b) {
                            const float inv = sinvC[b];
                            const float* srow = W + (size_t)(DD - 1 - b) * DD;
                            #pragma unroll
                            for (int yi = 0; yi < 4; ++yi) {
                                const int y = (ybase + yi < DD) ? (ybase + yi) : (DD - 1);
                                const float cy = srow[DD - 1 - y];
                                #pragma unroll
                                for (int zi = 0; zi < 4; ++zi) {
                                    const int z = (zbase + 16 * zi < DD) ? (zbase + 16 * zi) : (DD - 1);
                                    const float cz = srow[DD - 1 - z];
                                    float c = inv * (cy * cz);
                                    wv[yi][zi] = wv[yi][zi] - c;
                                }
                            }
                        }
                        #pragma unroll
                        for (int yi = 0; yi < 4; ++yi) {
                            const int y = ybase + yi;
                            #pragma unroll
                            for (int zi = 0; zi < 4; ++zi) {
                                const int z = zbase + 16 * zi;
                                if (y < DD && z < DD && z >= y)
                                    A[(size_t)y * DD + z] = wv[yi][zi];
                            }
                        }
                    }
                }
            }
        }
        __syncthreads();

        xbase = pos + 1;
    }
}

extern "C" void kernel_launch(void* const* d_in, const int* in_sizes, int n_in,
                              void* d_out, int out_size, void* d_ws, size_t ws_size,
                              hipStream_t stream) {
    const float* eig = (const float*)d_in[0];
    const float* u   = (const float*)d_in[1];
    float* out = (float*)d_out;
    float* A = (float*)d_ws;
    float* W = A + (size_t)DD * DD;   // upper: spec trailing; strict lower: pivot-row stash
    build_A_kernel<<<(DD * DD + 255) / 256, 256, 0, stream>>>(eig, A);
    sampler_kernel<<<1, 1024, 0, stream>>>(u, A, W, out);
}